// Round 4
// baseline (56.041 us; speedup 1.0000x reference)
//
#include <hip/hip_runtime.h>
#include <hip/hip_bf16.h>
#include <stdint.h>

#define IN_F 2048
#define OUT_F 128
#define KD 32
#define NR 256
#define OC 2176          // IN_F + OUT_F
#define OD 4096          // OUT_F * KD
#define NSPLIT 4
#define NHS 16           // half-steps (32k each) per K-split: 2048/32/NSPLIT

typedef __bf16 bf16x8 __attribute__((ext_vector_type(8)));
typedef float  f32x4  __attribute__((ext_vector_type(4)));

// ---------------------------------------------------------------------------
// Fused prep (grid = 4096 + 256 blocks):
//  part A (bid < 4096): Tb = bf16(T) in MFMA B-frag order.
//    chunk c = kt*256 + ot (kt: 32-k tile, ot: 16-o tile); within chunk,
//    lane l (fg=l>>4, fr=l&15) holds T[kt*32+fg*8+i][ot*16+fr], i=0..7.
//    Thread u = c*64 + l writes bf16x8 at Tb + u*8 (16B contiguous/lane).
//  part B: copy x -> out[:, 0:2048] and xb2 = bf16(x) in MFMA A-frag order
//    (chunk q = (h*4+fg)*256 + row holds x[row][h*32+fg*8 .. +8]).
// ---------------------------------------------------------------------------
__global__ __launch_bounds__(256) void prep_kernel(const float* __restrict__ x,
                                                   const float* __restrict__ Tm,
                                                   float* __restrict__ out,
                                                   __bf16* __restrict__ xb2,
                                                   __bf16* __restrict__ Tb) {
    const int bid = blockIdx.x;
    if (bid < 4096) {
        const int u     = bid * 256 + threadIdx.x;   // 0 .. 1M-1
        const int l     = u & 63;
        const int chunk = u >> 6;                    // 0 .. 16383
        const int ot    = chunk & 255;
        const int kt    = chunk >> 8;                // 0 .. 63
        const int fr = l & 15, fg = l >> 4;
        const float* src = Tm + (size_t)(kt * 32 + fg * 8) * OD + ot * 16 + fr;
        bf16x8 p;
        #pragma unroll
        for (int i = 0; i < 8; ++i) p[i] = (__bf16)src[(size_t)i * OD];
        *reinterpret_cast<bf16x8*>(Tb + (size_t)u * 8) = p;
    } else {
        const int q   = (bid - 4096) * 256 + threadIdx.x;  // 0 .. 65535
        const int row = q & 255;
        const int k0  = (q >> 8) << 3;
        const float* src = &x[row * IN_F + k0];
        float4 v0 = *reinterpret_cast<const float4*>(src);
        float4 v1 = *reinterpret_cast<const float4*>(src + 4);
        *reinterpret_cast<float4*>(&out[row * OC + k0])     = v0;
        *reinterpret_cast<float4*>(&out[row * OC + k0 + 4]) = v1;
        bf16x8 p = { (__bf16)v0.x, (__bf16)v0.y, (__bf16)v0.z, (__bf16)v0.w,
                     (__bf16)v1.x, (__bf16)v1.y, (__bf16)v1.z, (__bf16)v1.w };
        *reinterpret_cast<bf16x8*>(&xb2[(size_t)q * 8]) = p;
    }
}

// ---------------------------------------------------------------------------
// GEMM: Mt[o][n] = sum_k x[n][k]*T[k][o]. Pure fragment stream, no LDS.
// Block = 512 threads = 8 waves; wave w owns n in [w*32, w*32+32) (mi=0,1)
// and o in [bo*64, bo*64+64) (oi=0..3). grid = (64 o-blocks, NSPLIT).
// Per half-step: 2 A-frag + 4 B-frag b128 loads (all coalesced) -> 8 MFMA.
// 3-deep register prefetch via 4 rotating frag sets.
// ---------------------------------------------------------------------------
struct Frag { bf16x8 a0, a1, b0, b1, b2, b3; };

__device__ __forceinline__ Frag load_frag(const __bf16* __restrict__ xb2,
                                          const __bf16* __restrict__ Tb,
                                          int h, int n0, int bo4, int lane) {
    const int fr = lane & 15, fg = lane >> 4;
    Frag f;
    const __bf16* ab = xb2 + ((size_t)(h * 4 + fg) * 256 + n0 + fr) * 8;
    f.a0 = *reinterpret_cast<const bf16x8*>(ab);
    f.a1 = *reinterpret_cast<const bf16x8*>(ab + 128);       // +16 rows
    const __bf16* bb = Tb + ((size_t)(h * 256 + bo4) * 64 + lane) * 8;
    f.b0 = *reinterpret_cast<const bf16x8*>(bb);
    f.b1 = *reinterpret_cast<const bf16x8*>(bb + 512);       // next o-tile chunk
    f.b2 = *reinterpret_cast<const bf16x8*>(bb + 1024);
    f.b3 = *reinterpret_cast<const bf16x8*>(bb + 1536);
    return f;
}

__device__ __forceinline__ void comp(const Frag& f, f32x4 acc[2][4]) {
    acc[0][0] = __builtin_amdgcn_mfma_f32_16x16x32_bf16(f.a0, f.b0, acc[0][0], 0, 0, 0);
    acc[1][0] = __builtin_amdgcn_mfma_f32_16x16x32_bf16(f.a1, f.b0, acc[1][0], 0, 0, 0);
    acc[0][1] = __builtin_amdgcn_mfma_f32_16x16x32_bf16(f.a0, f.b1, acc[0][1], 0, 0, 0);
    acc[1][1] = __builtin_amdgcn_mfma_f32_16x16x32_bf16(f.a1, f.b1, acc[1][1], 0, 0, 0);
    acc[0][2] = __builtin_amdgcn_mfma_f32_16x16x32_bf16(f.a0, f.b2, acc[0][2], 0, 0, 0);
    acc[1][2] = __builtin_amdgcn_mfma_f32_16x16x32_bf16(f.a1, f.b2, acc[1][2], 0, 0, 0);
    acc[0][3] = __builtin_amdgcn_mfma_f32_16x16x32_bf16(f.a0, f.b3, acc[0][3], 0, 0, 0);
    acc[1][3] = __builtin_amdgcn_mfma_f32_16x16x32_bf16(f.a1, f.b3, acc[1][3], 0, 0, 0);
}

__global__ __launch_bounds__(512) void gemm_kernel(const __bf16* __restrict__ xb2,
                                                   const __bf16* __restrict__ Tb,
                                                   float* __restrict__ Mt) {
    const int tid  = threadIdx.x;
    const int lane = tid & 63;
    const int w    = tid >> 6;
    const int fr   = lane & 15, fg = lane >> 4;
    const int bo4  = blockIdx.x * 4;          // 16-o tile base index
    const int kc   = blockIdx.y;
    const int n0   = w * 32;
    const int h0   = kc * NHS;
    float* dst = Mt + (size_t)kc * OD * NR;

    f32x4 acc[2][4] = {};

    Frag s0 = load_frag(xb2, Tb, h0 + 0, n0, bo4, lane);
    Frag s1 = load_frag(xb2, Tb, h0 + 1, n0, bo4, lane);
    Frag s2 = load_frag(xb2, Tb, h0 + 2, n0, bo4, lane);

    for (int h = 0; h < NHS - 4; h += 4) {
        Frag s3 = load_frag(xb2, Tb, h0 + h + 3, n0, bo4, lane);
        comp(s0, acc);
        s0 = load_frag(xb2, Tb, h0 + h + 4, n0, bo4, lane);
        comp(s1, acc);
        s1 = load_frag(xb2, Tb, h0 + h + 5, n0, bo4, lane);
        comp(s2, acc);
        s2 = load_frag(xb2, Tb, h0 + h + 6, n0, bo4, lane);
        comp(s3, acc);
    }
    {
        Frag s3 = load_frag(xb2, Tb, h0 + NHS - 1, n0, bo4, lane);
        comp(s0, acc);
        comp(s1, acc);
        comp(s2, acc);
        comp(s3, acc);
    }

    // epilogue: D[row=n][col=o] -> dst[o*256 + n]
    #pragma unroll
    for (int mi = 0; mi < 2; ++mi) {
        #pragma unroll
        for (int oi = 0; oi < 4; ++oi) {
            const int o = (bo4 + oi) * 16 + fr;
            *reinterpret_cast<f32x4*>(&dst[(size_t)o * NR + n0 + mi * 16 + fg * 4]) = acc[mi][oi];
        }
    }
}

// ---------------------------------------------------------------------------
// Pairwise: o_b[j,f] = sum_i exp(-sum_d |M[i,f,d]-M[j,f,d]|), f32 (proven).
// Sums NSPLIT split-K partials during staging. grid (128 f, 4 j-quarters).
// ---------------------------------------------------------------------------
__global__ __launch_bounds__(256, 2) void pairwise_kernel(const float* __restrict__ Mt,
                                                          float* __restrict__ out) {
    __shared__ float Mf[256][36];
    __shared__ float part[4][64];

    const int f    = blockIdx.x;
    const int jq   = blockIdx.y;
    const int tid  = threadIdx.x;
    const int lane = tid & 63;
    const int wid  = tid >> 6;

    #pragma unroll
    for (int d = 0; d < 32; ++d) {
        float v = 0.f;
        #pragma unroll
        for (int s = 0; s < NSPLIT; ++s)
            v += Mt[(size_t)s * OD * NR + (f * KD + d) * NR + tid];
        Mf[tid][d] = v;
    }
    __syncthreads();

    const int j = jq * 64 + lane;
    float mj[32];
    #pragma unroll
    for (int d4 = 0; d4 < 8; ++d4) {
        f32x4 v = *reinterpret_cast<const f32x4*>(&Mf[j][d4 * 4]);
        mj[d4 * 4]     = v[0];
        mj[d4 * 4 + 1] = v[1];
        mj[d4 * 4 + 2] = v[2];
        mj[d4 * 4 + 3] = v[3];
    }

    float acc = 0.f;
    const int i0 = wid * 64;
    for (int ii = 0; ii < 64; ++ii) {
        const int i = i0 + ii;
        float norm = 0.f;
        #pragma unroll
        for (int d4 = 0; d4 < 8; ++d4) {
            f32x4 v = *reinterpret_cast<const f32x4*>(&Mf[i][d4 * 4]);
            norm += fabsf(v[0] - mj[d4 * 4]);
            norm += fabsf(v[1] - mj[d4 * 4 + 1]);
            norm += fabsf(v[2] - mj[d4 * 4 + 2]);
            norm += fabsf(v[3] - mj[d4 * 4 + 3]);
        }
        acc += __expf(-norm);
    }

    part[wid][lane] = acc;
    __syncthreads();
    if (tid < 64) {
        float s = part[0][tid] + part[1][tid] + part[2][tid] + part[3][tid];
        const int jj = jq * 64 + tid;
        out[jj * OC + IN_F + f] = s;
    }
}

extern "C" void kernel_launch(void* const* d_in, const int* in_sizes, int n_in,
                              void* d_out, int out_size, void* d_ws, size_t ws_size,
                              hipStream_t stream) {
    const float* x  = (const float*)d_in[0];   // [256, 2048] f32
    const float* Tm = (const float*)d_in[1];   // [2048, 4096] f32
    float* out = (float*)d_out;                // [256, 2176] f32
    char*  ws  = (char*)d_ws;

    __bf16* xb2 = (__bf16*)ws;                      // 1 MB  A-frag image of x
    __bf16* Tb  = (__bf16*)(ws + (1u << 20));       // 16 MB B-frag image of T
    float*  Mt  = (float*)(ws + (17u << 20));       // NSPLIT x 4 MB partials

    prep_kernel<<<dim3(4096 + 256), 256, 0, stream>>>(x, Tm, out, xb2, Tb);
    gemm_kernel<<<dim3(64, NSPLIT), 512, 0, stream>>>(xb2, Tb, Mt);
    pairwise_kernel<<<dim3(128, 4), 256, 0, stream>>>(Mt, out);
}

// Round 5
// 47.899 us; speedup vs baseline: 1.1700x; 1.1700x over previous
//
#include <hip/hip_runtime.h>
#include <hip/hip_bf16.h>
#include <stdint.h>

#define IN_F 2048
#define OUT_F 128
#define KD 32
#define NR 256
#define OC 2176          // IN_F + OUT_F
#define OD 4096          // OUT_F * KD
#define KSPLIT 8
#define HSPLIT 8         // 32-k half-steps per split (64 total / KSPLIT)

typedef __bf16 bf16x8 __attribute__((ext_vector_type(8)));
typedef __bf16 bf16x4 __attribute__((ext_vector_type(4)));
typedef float  f32x4  __attribute__((ext_vector_type(4)));

// ---------------------------------------------------------------------------
// Prep (grid = 4096 + 256 blocks; proven in R4):
//  bid < 4096: Tb = bf16(T) in MFMA B-frag order.
//    chunk c = kt*256 + ot; lane l (fg=l>>4, fr=l&15) holds
//    T[kt*32+fg*8+i][ot*16+fr], i=0..7, at Tb + (c*64+l)*8.
//  bid >= 4096: copy x -> out[:, 0:2048]; xb2 = bf16(x) in A-frag order
//    (chunk q = (h*4+fg)*256 + row holds x[row][h*32+fg*8 .. +8]).
// ---------------------------------------------------------------------------
__global__ __launch_bounds__(256) void prep_kernel(const float* __restrict__ x,
                                                   const float* __restrict__ Tm,
                                                   float* __restrict__ out,
                                                   __bf16* __restrict__ xb2,
                                                   __bf16* __restrict__ Tb) {
    const int bid = blockIdx.x;
    if (bid < 4096) {
        const int u     = bid * 256 + threadIdx.x;
        const int l     = u & 63;
        const int chunk = u >> 6;
        const int ot    = chunk & 255;
        const int kt    = chunk >> 8;
        const int fr = l & 15, fg = l >> 4;
        const float* src = Tm + (size_t)(kt * 32 + fg * 8) * OD + ot * 16 + fr;
        bf16x8 p;
        #pragma unroll
        for (int i = 0; i < 8; ++i) p[i] = (__bf16)src[(size_t)i * OD];
        *reinterpret_cast<bf16x8*>(Tb + (size_t)u * 8) = p;
    } else {
        const int q   = (bid - 4096) * 256 + threadIdx.x;
        const int row = q & 255;
        const int k0  = (q >> 8) << 3;
        const float* src = &x[row * IN_F + k0];
        float4 v0 = *reinterpret_cast<const float4*>(src);
        float4 v1 = *reinterpret_cast<const float4*>(src + 4);
        *reinterpret_cast<float4*>(&out[row * OC + k0])     = v0;
        *reinterpret_cast<float4*>(&out[row * OC + k0 + 4]) = v1;
        bf16x8 p = { (__bf16)v0.x, (__bf16)v0.y, (__bf16)v0.z, (__bf16)v0.w,
                     (__bf16)v1.x, (__bf16)v1.y, (__bf16)v1.z, (__bf16)v1.w };
        *reinterpret_cast<bf16x8*>(&xb2[(size_t)q * 8]) = p;
    }
}

// ---------------------------------------------------------------------------
// GEMM: Mtb[ks][o][n] (bf16 partials) = sum_k x[n][k]*T[k][o] over k-split ks.
// 256-thr blocks, 4 independent waves (no LDS, no barriers). Wave tile:
// 32n x 64o. Block tile: 128n x 64o. grid (64 bo, 2 bn, 8 ks) = 1024 blocks
// -> 4 blocks/CU, 4 waves/SIMD: latency hidden by TLP. 2-deep reg prefetch.
// Per half-step: 2 A-frag + 4 B-frag b128 loads -> 8 MFMA.
// ---------------------------------------------------------------------------
struct Frag { bf16x8 a0, a1, b0, b1, b2, b3; };

__device__ __forceinline__ Frag load_frag(const __bf16* __restrict__ xb2,
                                          const __bf16* __restrict__ Tb,
                                          int h, int n0, int c4, int lane) {
    const int fr = lane & 15, fg = lane >> 4;
    Frag f;
    const __bf16* ab = xb2 + ((size_t)(h * 4 + fg) * 256 + n0 + fr) * 8;
    f.a0 = *reinterpret_cast<const bf16x8*>(ab);
    f.a1 = *reinterpret_cast<const bf16x8*>(ab + 128);      // n0 + 16
    const __bf16* bb = Tb + ((size_t)(h * 256 + c4) * 64 + lane) * 8;
    f.b0 = *reinterpret_cast<const bf16x8*>(bb);
    f.b1 = *reinterpret_cast<const bf16x8*>(bb + 512);
    f.b2 = *reinterpret_cast<const bf16x8*>(bb + 1024);
    f.b3 = *reinterpret_cast<const bf16x8*>(bb + 1536);
    return f;
}

__device__ __forceinline__ void comp(const Frag& f, f32x4 acc[2][4]) {
    acc[0][0] = __builtin_amdgcn_mfma_f32_16x16x32_bf16(f.a0, f.b0, acc[0][0], 0, 0, 0);
    acc[1][0] = __builtin_amdgcn_mfma_f32_16x16x32_bf16(f.a1, f.b0, acc[1][0], 0, 0, 0);
    acc[0][1] = __builtin_amdgcn_mfma_f32_16x16x32_bf16(f.a0, f.b1, acc[0][1], 0, 0, 0);
    acc[1][1] = __builtin_amdgcn_mfma_f32_16x16x32_bf16(f.a1, f.b1, acc[1][1], 0, 0, 0);
    acc[0][2] = __builtin_amdgcn_mfma_f32_16x16x32_bf16(f.a0, f.b2, acc[0][2], 0, 0, 0);
    acc[1][2] = __builtin_amdgcn_mfma_f32_16x16x32_bf16(f.a1, f.b2, acc[1][2], 0, 0, 0);
    acc[0][3] = __builtin_amdgcn_mfma_f32_16x16x32_bf16(f.a0, f.b3, acc[0][3], 0, 0, 0);
    acc[1][3] = __builtin_amdgcn_mfma_f32_16x16x32_bf16(f.a1, f.b3, acc[1][3], 0, 0, 0);
}

__global__ __launch_bounds__(256, 4) void gemm_kernel(const __bf16* __restrict__ xb2,
                                                      const __bf16* __restrict__ Tb,
                                                      __bf16* __restrict__ Mtb) {
    const int tid  = threadIdx.x;
    const int lane = tid & 63;
    const int wid  = tid >> 6;
    const int fr   = lane & 15, fg = lane >> 4;
    const int c4   = blockIdx.x * 4;                 // 16-o chunk base (o-span 64)
    const int n0   = blockIdx.y * 128 + wid * 32;    // wave n base
    const int ks   = blockIdx.z;
    const int h0   = ks * HSPLIT;
    __bf16* dst = Mtb + (size_t)ks * OD * NR;

    f32x4 acc[2][4] = {};

    Frag s0 = load_frag(xb2, Tb, h0 + 0, n0, c4, lane);
    Frag s1 = load_frag(xb2, Tb, h0 + 1, n0, c4, lane);

    comp(s0, acc); s0 = load_frag(xb2, Tb, h0 + 2, n0, c4, lane);
    comp(s1, acc); s1 = load_frag(xb2, Tb, h0 + 3, n0, c4, lane);
    comp(s0, acc); s0 = load_frag(xb2, Tb, h0 + 4, n0, c4, lane);
    comp(s1, acc); s1 = load_frag(xb2, Tb, h0 + 5, n0, c4, lane);
    comp(s0, acc); s0 = load_frag(xb2, Tb, h0 + 6, n0, c4, lane);
    comp(s1, acc); s1 = load_frag(xb2, Tb, h0 + 7, n0, c4, lane);
    comp(s0, acc);
    comp(s1, acc);

    // epilogue: D[row=n][col=o] -> dst[o*256 + n] as bf16 (4 consecutive n)
    #pragma unroll
    for (int mi = 0; mi < 2; ++mi) {
        #pragma unroll
        for (int oi = 0; oi < 4; ++oi) {
            const int o  = (c4 + oi) * 16 + fr;
            const int nb = n0 + mi * 16 + fg * 4;
            bf16x4 v = { (__bf16)acc[mi][oi][0], (__bf16)acc[mi][oi][1],
                         (__bf16)acc[mi][oi][2], (__bf16)acc[mi][oi][3] };
            *reinterpret_cast<bf16x4*>(&dst[(size_t)o * NR + nb]) = v;
        }
    }
}

// ---------------------------------------------------------------------------
// Pairwise: o_b[j,f] = sum_i exp(-sum_d |M[i,f,d]-M[j,f,d]|).
// Sums the 8 bf16 split-K partials in f32 during staging (diagonal stays
// exactly 0 -> exp(0)=1 exact). grid (128 f, 4 j-quarters), 256 thr.
// ---------------------------------------------------------------------------
__global__ __launch_bounds__(256, 2) void pairwise_kernel(const __bf16* __restrict__ Mtb,
                                                          float* __restrict__ out) {
    __shared__ float Mf[256][36];
    __shared__ float part[4][64];

    const int f    = blockIdx.x;
    const int jq   = blockIdx.y;
    const int tid  = threadIdx.x;
    const int lane = tid & 63;
    const int wid  = tid >> 6;

    #pragma unroll
    for (int d = 0; d < 32; ++d) {
        float v = 0.f;
        #pragma unroll
        for (int s = 0; s < KSPLIT; ++s)
            v += (float)Mtb[(size_t)s * OD * NR + (f * KD + d) * NR + tid];
        Mf[tid][d] = v;
    }
    __syncthreads();

    const int j = jq * 64 + lane;
    float mj[32];
    #pragma unroll
    for (int d4 = 0; d4 < 8; ++d4) {
        f32x4 v = *reinterpret_cast<const f32x4*>(&Mf[j][d4 * 4]);
        mj[d4 * 4]     = v[0];
        mj[d4 * 4 + 1] = v[1];
        mj[d4 * 4 + 2] = v[2];
        mj[d4 * 4 + 3] = v[3];
    }

    float acc = 0.f;
    const int i0 = wid * 64;
    for (int ii = 0; ii < 64; ++ii) {
        const int i = i0 + ii;
        float norm = 0.f;
        #pragma unroll
        for (int d4 = 0; d4 < 8; ++d4) {
            f32x4 v = *reinterpret_cast<const f32x4*>(&Mf[i][d4 * 4]);
            norm += fabsf(v[0] - mj[d4 * 4]);
            norm += fabsf(v[1] - mj[d4 * 4 + 1]);
            norm += fabsf(v[2] - mj[d4 * 4 + 2]);
            norm += fabsf(v[3] - mj[d4 * 4 + 3]);
        }
        acc += __expf(-norm);
    }

    part[wid][lane] = acc;
    __syncthreads();
    if (tid < 64) {
        float s = part[0][tid] + part[1][tid] + part[2][tid] + part[3][tid];
        const int jj = jq * 64 + tid;
        out[jj * OC + IN_F + f] = s;
    }
}

extern "C" void kernel_launch(void* const* d_in, const int* in_sizes, int n_in,
                              void* d_out, int out_size, void* d_ws, size_t ws_size,
                              hipStream_t stream) {
    const float* x  = (const float*)d_in[0];   // [256, 2048] f32
    const float* Tm = (const float*)d_in[1];   // [2048, 4096] f32
    float* out = (float*)d_out;                // [256, 2176] f32
    char*  ws  = (char*)d_ws;

    __bf16* xb2 = (__bf16*)ws;                      // 1 MB  A-frag image of x
    __bf16* Tb  = (__bf16*)(ws + (1u << 20));       // 16 MB B-frag image of T
    __bf16* Mtb = (__bf16*)(ws + (17u << 20));      // 16 MB: 8 bf16 partials

    prep_kernel<<<dim3(4096 + 256), 256, 0, stream>>>(x, Tm, out, xb2, Tb);
    gemm_kernel<<<dim3(64, 2, KSPLIT), 256, 0, stream>>>(xb2, Tb, Mtb);
    pairwise_kernel<<<dim3(128, 4), 256, 0, stream>>>(Mtb, out);
}

// Round 6
// 45.427 us; speedup vs baseline: 1.2337x; 1.0544x over previous
//
#include <hip/hip_runtime.h>
#include <hip/hip_bf16.h>
#include <stdint.h>

#define IN_F 2048
#define OUT_F 128
#define KD 32
#define NR 256
#define OC 2176          // IN_F + OUT_F
#define OD 4096          // OUT_F * KD
#define NSTEP 32         // K-steps of 32k per block (K=1024 per split, ks=2)

typedef __bf16 bf16x8 __attribute__((ext_vector_type(8)));
typedef __bf16 bf16x4 __attribute__((ext_vector_type(4)));
typedef float  f32x4  __attribute__((ext_vector_type(4)));

// ---------------------------------------------------------------------------
// Prep (256 blocks): copy x -> out[:, 0:2048]; xb2 = bf16(x) in MFMA A-frag
// order: chunk q = (k0>>3)*256 + row holds x[row][k0..k0+8) (proven R2-R5).
// ---------------------------------------------------------------------------
__global__ __launch_bounds__(256) void prep_kernel(const float* __restrict__ x,
                                                   float* __restrict__ out,
                                                   __bf16* __restrict__ xb2) {
    const int q   = blockIdx.x * 256 + threadIdx.x;   // 0..65535
    const int row = q & 255;
    const int k0  = (q >> 8) << 3;
    const float* src = &x[row * IN_F + k0];
    float4 v0 = *reinterpret_cast<const float4*>(src);
    float4 v1 = *reinterpret_cast<const float4*>(src + 4);
    *reinterpret_cast<float4*>(&out[row * OC + k0])     = v0;
    *reinterpret_cast<float4*>(&out[row * OC + k0 + 4]) = v1;
    bf16x8 p = { (__bf16)v0.x, (__bf16)v0.y, (__bf16)v0.z, (__bf16)v0.w,
                 (__bf16)v1.x, (__bf16)v1.y, (__bf16)v1.z, (__bf16)v1.w };
    *reinterpret_cast<bf16x8*>(&xb2[(size_t)q * 8]) = p;
}

// ---------------------------------------------------------------------------
// GEMM: Mt[o][n] = sum_k x[n][k]*T[k][o], split-K=2, T read DIRECTLY.
// grid (128 o-tiles, 4 n-tiles, 2 ks) = 1024 blocks, 256 thr (4 waves).
// Wave tile 16n x 32o (2 MFMA/step). Per step: stage T 32kx32o f32 -> bf16
// LDS Bs[o][k] (transposed, stride 40); A-frags b128 from xb2; raw s_barrier
// + lgkmcnt(0) only (global prefetch stays in flight: B 3-deep, A 2-deep).
// ---------------------------------------------------------------------------
__global__ __launch_bounds__(256, 4) void gemm_kernel(const __bf16* __restrict__ xb2,
                                                      const float* __restrict__ Tm,
                                                      float* __restrict__ Mt) {
    __shared__ __bf16 Bs[2][32][40];

    const int tid  = threadIdx.x;
    const int lane = tid & 63;
    const int wid  = tid >> 6;
    const int fr   = lane & 15, fg = lane >> 4;
    const int o0   = blockIdx.x * 32;
    const int n0   = blockIdx.y * 64 + wid * 16;
    const int ks   = blockIdx.z;

    float* dst = Mt + (size_t)ks * OD * NR;

    // staging map: thread -> (o, 4 consecutive k)
    const int ow = tid & 31;
    const int k4 = (tid >> 5) << 2;                   // 0,4,...,28
    const float* tb = Tm + (size_t)(ks * 1024 + k4) * OD + o0 + ow;

    // A-frag base: xb2 chunk ((h*4+fg)*256 + n0+fr), h = ks*32 + t
    const __bf16* ab = xb2 + ((size_t)((ks * 32) * 4 + fg) * 256 + n0 + fr) * 8;

    f32x4 acc[2] = {};

#define LOADB(t) ({ const float* s_ = tb + (size_t)(t) * 32 * OD;            \
                    float4 p_; p_.x = s_[0]; p_.y = s_[OD];                  \
                    p_.z = s_[2 * OD]; p_.w = s_[3 * OD]; p_; })
#define LOADA(t) (*reinterpret_cast<const bf16x8*>(ab + (size_t)(t) * 8192))
#define WRITEB(buf, p) do {                                                  \
        bf16x4 v_ = { (__bf16)(p).x, (__bf16)(p).y, (__bf16)(p).z, (__bf16)(p).w }; \
        *reinterpret_cast<bf16x4*>(&Bs[buf][ow][k4]) = v_; } while (0)

    float4 p1, p2;
    {
        float4 p0 = LOADB(0);
        p1 = LOADB(1);
        p2 = LOADB(2);
        WRITEB(0, p0);
    }
    bf16x8 a0 = LOADA(0);
    bf16x8 a1 = LOADA(1);

    asm volatile("s_waitcnt lgkmcnt(0)" ::: "memory");
    __builtin_amdgcn_s_barrier();
    asm volatile("" ::: "memory");

    for (int t = 0; t < NSTEP; ++t) {
        const int buf = t & 1;
        // compute current step
        bf16x8 b0 = *reinterpret_cast<const bf16x8*>(&Bs[buf][fr][fg * 8]);
        bf16x8 b1 = *reinterpret_cast<const bf16x8*>(&Bs[buf][16 + fr][fg * 8]);
        acc[0] = __builtin_amdgcn_mfma_f32_16x16x32_bf16(a0, b0, acc[0], 0, 0, 0);
        acc[1] = __builtin_amdgcn_mfma_f32_16x16x32_bf16(a0, b1, acc[1], 0, 0, 0);

        if (t < NSTEP - 1) {
            WRITEB(buf ^ 1, p1);                       // stage step t+1
            p1 = p2;
            if (t + 3 < NSTEP) p2 = LOADB(t + 3);      // 3-deep B prefetch
            a0 = a1;
            if (t + 2 < NSTEP) a1 = LOADA(t + 2);      // 2-deep A prefetch
            asm volatile("s_waitcnt lgkmcnt(0)" ::: "memory");
            __builtin_amdgcn_s_barrier();
            asm volatile("" ::: "memory");
        }
    }
#undef LOADB
#undef LOADA
#undef WRITEB

    // epilogue: D[row=n][col=o] -> dst[o*256 + n]; 4 consecutive n per lane
    #pragma unroll
    for (int oi = 0; oi < 2; ++oi) {
        const int o = o0 + oi * 16 + fr;
        *reinterpret_cast<f32x4*>(&dst[(size_t)o * NR + n0 + fg * 4]) = acc[oi];
    }
}

// ---------------------------------------------------------------------------
// Pairwise (R2-exact, proven): o_b[j,f] = sum_i exp(-sum_d |M[i,f,d]-M[j,f,d]|)
// f32, 2 split-K partials summed during staging. grid (128 f, 4 j-quarters).
// ---------------------------------------------------------------------------
__global__ __launch_bounds__(256, 2) void pairwise_kernel(const float* __restrict__ Mt0,
                                                          const float* __restrict__ Mt1,
                                                          float* __restrict__ out) {
    __shared__ float Mf[256][36];
    __shared__ float part[4][64];

    const int f    = blockIdx.x;
    const int jq   = blockIdx.y;
    const int tid  = threadIdx.x;
    const int lane = tid & 63;
    const int wid  = tid >> 6;

    #pragma unroll
    for (int d = 0; d < 32; ++d)
        Mf[tid][d] = Mt0[(f * KD + d) * NR + tid] + Mt1[(f * KD + d) * NR + tid];
    __syncthreads();

    const int j = jq * 64 + lane;
    float mj[32];
    #pragma unroll
    for (int d4 = 0; d4 < 8; ++d4) {
        f32x4 v = *reinterpret_cast<const f32x4*>(&Mf[j][d4 * 4]);
        mj[d4 * 4]     = v[0];
        mj[d4 * 4 + 1] = v[1];
        mj[d4 * 4 + 2] = v[2];
        mj[d4 * 4 + 3] = v[3];
    }

    float acc = 0.f;
    const int i0 = wid * 64;
    for (int ii = 0; ii < 64; ++ii) {
        const int i = i0 + ii;
        float norm = 0.f;
        #pragma unroll
        for (int d4 = 0; d4 < 8; ++d4) {
            f32x4 v = *reinterpret_cast<const f32x4*>(&Mf[i][d4 * 4]);
            norm += fabsf(v[0] - mj[d4 * 4]);
            norm += fabsf(v[1] - mj[d4 * 4 + 1]);
            norm += fabsf(v[2] - mj[d4 * 4 + 2]);
            norm += fabsf(v[3] - mj[d4 * 4 + 3]);
        }
        acc += __expf(-norm);
    }

    part[wid][lane] = acc;
    __syncthreads();
    if (tid < 64) {
        float s = part[0][tid] + part[1][tid] + part[2][tid] + part[3][tid];
        const int jj = jq * 64 + tid;
        out[jj * OC + IN_F + f] = s;
    }
}

extern "C" void kernel_launch(void* const* d_in, const int* in_sizes, int n_in,
                              void* d_out, int out_size, void* d_ws, size_t ws_size,
                              hipStream_t stream) {
    const float* x  = (const float*)d_in[0];   // [256, 2048] f32
    const float* Tm = (const float*)d_in[1];   // [2048, 4096] f32
    float* out = (float*)d_out;                // [256, 2176] f32
    char*  ws  = (char*)d_ws;

    float*  Mt0 = (float*)ws;                       // 4 MB split-K partial 0
    float*  Mt1 = (float*)(ws + (4u << 20));        // 4 MB split-K partial 1
    __bf16* xb2 = (__bf16*)(ws + (8u << 20));       // 1 MB A-frag image of x

    prep_kernel<<<dim3(256), 256, 0, stream>>>(x, out, xb2);
    gemm_kernel<<<dim3(128, 4, 2), 256, 0, stream>>>(xb2, Tm, Mt0);
    pairwise_kernel<<<dim3(128, 4), 256, 0, stream>>>(Mt0, Mt1, out);
}